// Round 1
// baseline (843.382 us; speedup 1.0000x reference)
//
#include <hip/hip_runtime.h>

using u16 = unsigned short;
typedef __attribute__((ext_vector_type(8))) short bf16x8;
typedef __attribute__((ext_vector_type(4))) float f32x4;

#define DEVI __device__ __forceinline__

DEVI float bf2f(u16 u){ union{ unsigned v; float f; } x; x.v = ((unsigned)u)<<16; return x.f; }
DEVI u16 f2bf(float f){ union{ float f; unsigned v; } x; x.f = f;
  unsigned r = x.v + 0x7FFFu + ((x.v>>16)&1u); return (u16)(r>>16); }

DEVI float gelu_f(float x){
  float y = 0.7978845608028654f*(x + 0.044715f*x*x*x);
  y = fminf(fmaxf(y, -30.f), 30.f);
  float e = __expf(2.f*y);
  return 0.5f*x*(1.f + (e-1.f)/(e+1.f));
}

DEVI void gload_lds16(const void* g, void* l){
  __builtin_amdgcn_global_load_lds((const __attribute__((address_space(1))) void*)g,
                                   (__attribute__((address_space(3))) void*)l, 16, 0, 0);
}

// ---------------- weight convert + transpose: in[R][C] f32 -> out[C][R] bf16 ----
__global__ __launch_bounds__(256) void wconv_kernel(const float* __restrict__ in,
                                                    u16* __restrict__ out, int R, int C){
  __shared__ u16 t[32][33];
  int c0 = blockIdx.x*32, r0 = blockIdx.y*32;
  int tc = threadIdx.x & 31, tr = threadIdx.x >> 5;
  #pragma unroll
  for (int i=0;i<4;i++){
    int r = tr + i*8;
    t[r][tc] = f2bf(in[(size_t)(r0+r)*C + (c0+tc)]);
  }
  __syncthreads();
  #pragma unroll
  for (int i=0;i<4;i++){
    int r = tr + i*8;
    out[(size_t)(c0+r)*R + (r0+tc)] = t[tc][r];
  }
}

// ---------------- block reduction (sum, sumsq) over 256 threads --------------
DEVI void block_reduce2(float& s1, float& s2, int tid){
  #pragma unroll
  for (int off=1; off<64; off<<=1){ s1 += __shfl_xor(s1, off); s2 += __shfl_xor(s2, off); }
  __shared__ float red[8];
  int wid = tid>>6;
  if ((tid&63)==0){ red[wid*2]=s1; red[wid*2+1]=s2; }
  __syncthreads();
  s1 = red[0]+red[2]+red[4]+red[6];
  s2 = red[1]+red[3]+red[5]+red[7];
}

// ---------------- LN1: x fp32 -> bf16 normalized ------------------------------
__global__ __launch_bounds__(256) void ln_kernel(const float* __restrict__ x,
    const float* __restrict__ w, const float* __restrict__ b, u16* __restrict__ out){
  int row = blockIdx.x, tid = threadIdx.x;
  float4 v = ((const float4*)(x + (size_t)row*1024))[tid];
  float s1 = v.x+v.y+v.z+v.w;
  float s2 = v.x*v.x+v.y*v.y+v.z*v.z+v.w*v.w;
  block_reduce2(s1,s2,tid);
  float mean = s1*(1.f/1024.f);
  float var  = s2*(1.f/1024.f) - mean*mean;
  float inv  = rsqrtf(var + 1e-5f);
  float4 wv = ((const float4*)w)[tid];
  float4 bv = ((const float4*)b)[tid];
  ushort4 o;
  o.x = f2bf(wv.x*((v.x-mean)*inv)+bv.x);
  o.y = f2bf(wv.y*((v.y-mean)*inv)+bv.y);
  o.z = f2bf(wv.z*((v.z-mean)*inv)+bv.z);
  o.w = f2bf(wv.w*((v.w-mean)*inv)+bv.w);
  ((ushort4*)(out + (size_t)row*1024))[tid] = o;
}

// ---------------- residual + LN2: h=x+ctx (fp32 out), hb = LN(h) bf16 ---------
__global__ __launch_bounds__(256) void resln_kernel(const float* __restrict__ x,
    const u16* __restrict__ ctx, const float* __restrict__ w, const float* __restrict__ b,
    float* __restrict__ h, u16* __restrict__ hb){
  int row = blockIdx.x, tid = threadIdx.x;
  float4 xv = ((const float4*)(x + (size_t)row*1024))[tid];
  ushort4 cv = ((const ushort4*)(ctx + (size_t)row*1024))[tid];
  float4 hv;
  hv.x = xv.x + bf2f(cv.x); hv.y = xv.y + bf2f(cv.y);
  hv.z = xv.z + bf2f(cv.z); hv.w = xv.w + bf2f(cv.w);
  ((float4*)(h + (size_t)row*1024))[tid] = hv;
  float s1 = hv.x+hv.y+hv.z+hv.w;
  float s2 = hv.x*hv.x+hv.y*hv.y+hv.z*hv.z+hv.w*hv.w;
  block_reduce2(s1,s2,tid);
  float mean = s1*(1.f/1024.f);
  float var  = s2*(1.f/1024.f) - mean*mean;
  float inv  = rsqrtf(var + 1e-5f);
  float4 wv = ((const float4*)w)[tid];
  float4 bv = ((const float4*)b)[tid];
  ushort4 o;
  o.x = f2bf(wv.x*((hv.x-mean)*inv)+bv.x);
  o.y = f2bf(wv.y*((hv.y-mean)*inv)+bv.y);
  o.z = f2bf(wv.z*((hv.z-mean)*inv)+bv.z);
  o.w = f2bf(wv.w*((hv.w-mean)*inv)+bv.w);
  ((ushort4*)(hb + (size_t)row*1024))[tid] = o;
}

// ---------------- GEMM core: C[M,N] = A[M,K](bf16) * Bt[N,K](bf16)^T ----------
// m97 structure: BMxBN tile, BK=32, 4 waves, global_load_lds(16B), dbuf LDS.
template<int BM,int BN,int WM,int WN, class EpiF>
DEVI void gemm_core(const u16* __restrict__ A, const u16* __restrict__ Bt,
                    int K, int m0, int n0, EpiF epi){
  constexpr int WAVES_N = BN/WN;
  static_assert((BM/WM)*(BN/WN) == 4, "4 waves");
  constexpr int FM = WM/16, FN = WN/16;
  __shared__ u16 As[2][BM*32];
  __shared__ u16 Bs[2][BN*32];
  const int tid = threadIdx.x;
  const int wid = tid>>6, lane = tid&63;
  const int wr = wid / WAVES_N, wc = wid % WAVES_N;
  const int g = lane>>4, l16 = lane&15;
  f32x4 acc[FM][FN] = {};

  auto stage = [&](int buf, int t){
    #pragma unroll
    for (int j=0;j<BM/64;j++){
      int cbase = wid*BM + j*64;          // chunk base for this wave (16B chunks)
      int c = cbase + lane;
      int r = c>>2, c4 = c&3;             // 4 chunks per 64B row (BK=32 bf16)
      gload_lds16(A + (size_t)(m0+r)*K + t*32 + c4*8, &As[buf][cbase*8]);
    }
    #pragma unroll
    for (int j=0;j<BN/64;j++){
      int cbase = wid*BN + j*64;
      int c = cbase + lane;
      int r = c>>2, c4 = c&3;
      gload_lds16(Bt + (size_t)(n0+r)*K + t*32 + c4*8, &Bs[buf][cbase*8]);
    }
  };

  const int NT = K/32;
  stage(0,0);
  __syncthreads();
  for (int t=0;t<NT;t++){
    int cur = t&1;
    if (t+1 < NT) stage(cur^1, t+1);
    bf16x8 a[FM], b[FN];
    #pragma unroll
    for (int m=0;m<FM;m++) a[m] = *(const bf16x8*)&As[cur][(wr*WM + m*16 + l16)*32 + g*8];
    #pragma unroll
    for (int n=0;n<FN;n++) b[n] = *(const bf16x8*)&Bs[cur][(wc*WN + n*16 + l16)*32 + g*8];
    #pragma unroll
    for (int m=0;m<FM;m++)
      #pragma unroll
      for (int n=0;n<FN;n++)
        acc[m][n] = __builtin_amdgcn_mfma_f32_16x16x32_bf16(a[m], b[n], acc[m][n], 0,0,0);
    __syncthreads();
  }
  #pragma unroll
  for (int m=0;m<FM;m++)
    #pragma unroll
    for (int n=0;n<FN;n++){
      int row = m0 + wr*WM + m*16 + g*4;   // + r (0..3)
      int col = n0 + wc*WN + n*16 + l16;
      epi(row, col, acc[m][n]);
    }
}

// fused QKV: grid (32, 24); y selects {q,k,v} x 8 col-blocks
__global__ __launch_bounds__(256) void qkv_kernel(const u16* __restrict__ xn,
    const u16* __restrict__ wqt, const u16* __restrict__ wkt, const u16* __restrict__ wvt,
    u16* __restrict__ qo, u16* __restrict__ ko, u16* __restrict__ vo){
  int sel = blockIdx.y >> 3;
  const u16* Bt = (sel==0)?wqt:((sel==1)?wkt:wvt);
  u16* out = (sel==0)?qo:((sel==1)?ko:vo);
  gemm_core<128,128,64,64>(xn, Bt, 1024, blockIdx.x*128, (blockIdx.y&7)*128,
    [&](int row,int col,f32x4 v){
      #pragma unroll
      for (int r=0;r<4;r++) out[(size_t)(row+r)*1024 + col] = f2bf(v[r]);
    });
}

__global__ __launch_bounds__(256) void ffn1_kernel(const u16* __restrict__ hb,
    const u16* __restrict__ w1t, const float* __restrict__ b1, u16* __restrict__ gout){
  gemm_core<128,128,64,64>(hb, w1t, 1024, blockIdx.x*128, blockIdx.y*128,
    [&](int row,int col,f32x4 v){
      #pragma unroll
      for (int r=0;r<4;r++){
        float t = v[r] + b1[col];
        gout[(size_t)(row+r)*4096 + col] = f2bf(gelu_f(t));
      }
    });
}

__global__ __launch_bounds__(256) void ffn2_kernel(const u16* __restrict__ gin,
    const u16* __restrict__ w2t, const float* __restrict__ b2,
    const float* __restrict__ h, u16* __restrict__ hfb){
  gemm_core<64,128,32,64>(gin, w2t, 4096, blockIdx.x*64, blockIdx.y*128,
    [&](int row,int col,f32x4 v){
      #pragma unroll
      for (int r=0;r<4;r++){
        float t = h[(size_t)(row+r)*1024 + col] + v[r] + b2[col];
        hfb[(size_t)(row+r)*1024 + col] = f2bf(t);
      }
    });
}

__global__ __launch_bounds__(256) void proj_kernel(const u16* __restrict__ hfb,
    const u16* __restrict__ pwt, const float* __restrict__ pb, float* __restrict__ out){
  gemm_core<128,128,64,64>(hfb, pwt, 1024, blockIdx.x*128, blockIdx.y*128,
    [&](int row,int col,f32x4 v){
      #pragma unroll
      for (int r=0;r<4;r++) out[(size_t)(row+r)*32000 + col] = v[r] + pb[col];
    });
}

// ---------------- flash attention: B=2,H=16,S=2048,D=64, causal ---------------
// grid (32 = b*16+h, 32 = q-block of 64 rows), 256 thr; wave w owns 16 q-rows.
__global__ __launch_bounds__(256) void attn_kernel(const u16* __restrict__ q,
    const u16* __restrict__ k, const u16* __restrict__ v, u16* __restrict__ ctx){
  __shared__ u16 Qs[64*64], Ks[64*64], Vt[64*64];
  __shared__ u16 Ps[4][16*64];
  const int tid = threadIdx.x, lane = tid&63, wid = tid>>6;
  const int g = lane>>4, l16 = lane&15;
  const int b = blockIdx.x>>4, hh = blockIdx.x&15;
  const int qb = blockIdx.y;
  const size_t tokbase = (size_t)b*2048;
  const int hoff = hh*64;

  // stage Q tile (64 rows x 64 d), XOR-swizzled rows of 128B
  #pragma unroll
  for (int j=0;j<2;j++){
    int c = j*256 + tid;
    int r = c>>3, c8 = c&7;
    uint4 val = *(const uint4*)(q + (tokbase + qb*64 + r)*1024 + hoff + c8*8);
    *(uint4*)((char*)Qs + r*128 + ((c8*16) ^ ((r&7)<<4))) = val;
  }
  __syncthreads();
  bf16x8 qa[2];
  const int qrow_l = wid*16 + l16;
  #pragma unroll
  for (int kk=0;kk<2;kk++)
    qa[kk] = *(const bf16x8*)((const char*)Qs + qrow_l*128 + ((kk*64 + g*16) ^ ((qrow_l&7)<<4)));

  float m_r[4], l_r[4];
  f32x4 o_acc[4] = {};
  #pragma unroll
  for (int r=0;r<4;r++){ m_r[r] = -1e30f; l_r[r] = 0.f; }

  for (int kt=0; kt<=qb; kt++){
    __syncthreads();                       // prev-iter LDS reads complete
    const int kv0 = kt*64;
    #pragma unroll
    for (int j=0;j<2;j++){                 // K tile, row-major swizzled
      int c = j*256 + tid;
      int r = c>>3, c8 = c&7;
      uint4 val = *(const uint4*)(k + (tokbase + kv0 + r)*1024 + hoff + c8*8);
      *(uint4*)((char*)Ks + r*128 + ((c8*16) ^ ((r&7)<<4))) = val;
    }
    #pragma unroll
    for (int j=0;j<2;j++){                 // V tile, transposed [d][kv], swizzled
      int c = j*256 + tid;
      int kv = c>>3, d8 = c&7;
      union{ uint4 u; u16 s[8]; } uu;
      uu.u = *(const uint4*)(v + (tokbase + kv0 + kv)*1024 + hoff + d8*8);
      #pragma unroll
      for (int e=0;e<8;e++){
        int d = d8*8+e;
        *(u16*)((char*)Vt + d*128 + ((kv*2) ^ ((d&7)<<4))) = uu.s[e];
      }
    }
    __syncthreads();

    // QK^T : s[c][r] = scores[q = wid*16+g*4+r][kv = c*16+l16]
    f32x4 s[4] = {};
    #pragma unroll
    for (int c=0;c<4;c++){
      #pragma unroll
      for (int kk=0;kk<2;kk++){
        int krow = c*16 + l16;
        bf16x8 kb = *(const bf16x8*)((const char*)Ks + krow*128 + ((kk*64 + g*16) ^ ((krow&7)<<4)));
        s[c] = __builtin_amdgcn_mfma_f32_16x16x32_bf16(qa[kk], kb, s[c], 0,0,0);
      }
    }
    const int qrow0 = qb*64 + wid*16 + g*4;
    float sv[4][4];
    #pragma unroll
    for (int c=0;c<4;c++){
      #pragma unroll
      for (int r=0;r<4;r++){
        float xx = s[c][r] * 0.125f;
        if (kt==qb){
          int kvabs = kv0 + c*16 + l16;
          if (kvabs > qrow0 + r) xx = -1e30f;
        }
        sv[c][r] = xx;
      }
    }
    // online softmax per owned row (replicated across the 16 lanes of a row)
    #pragma unroll
    for (int r=0;r<4;r++){
      float rm = fmaxf(fmaxf(sv[0][r],sv[1][r]),fmaxf(sv[2][r],sv[3][r]));
      #pragma unroll
      for (int off=1; off<16; off<<=1) rm = fmaxf(rm, __shfl_xor(rm, off));
      float mn  = fmaxf(m_r[r], rm);
      float fac = __expf(m_r[r] - mn);
      float rs = 0.f;
      const int prow = g*4 + r;
      #pragma unroll
      for (int c=0;c<4;c++){
        float p = __expf(sv[c][r] - mn);
        rs += p;
        *(u16*)((char*)&Ps[wid][0] + prow*128 + (((c*16+l16)*2) ^ ((prow&7)<<4))) = f2bf(p);
      }
      #pragma unroll
      for (int off=1; off<16; off<<=1) rs += __shfl_xor(rs, off);
      m_r[r] = mn;
      l_r[r] = l_r[r]*fac + rs;
      #pragma unroll
      for (int c=0;c<4;c++) o_acc[c][r] *= fac;
    }
    // PV: A = P (rows = q), B = V^T tile
    bf16x8 pa[2];
    #pragma unroll
    for (int kk=0;kk<2;kk++)
      pa[kk] = *(const bf16x8*)((const char*)&Ps[wid][0] + l16*128 + ((kk*64 + g*16) ^ ((l16&7)<<4)));
    #pragma unroll
    for (int c=0;c<4;c++){
      #pragma unroll
      for (int kk=0;kk<2;kk++){
        int vrow = c*16 + l16;
        bf16x8 vb = *(const bf16x8*)((const char*)Vt + vrow*128 + ((kk*64 + g*16) ^ ((vrow&7)<<4)));
        o_acc[c] = __builtin_amdgcn_mfma_f32_16x16x32_bf16(pa[kk], vb, o_acc[c], 0,0,0);
      }
    }
  }
  #pragma unroll
  for (int c=0;c<4;c++){
    #pragma unroll
    for (int r=0;r<4;r++){
      float o = o_acc[c][r] / l_r[r];
      size_t tok = tokbase + qb*64 + wid*16 + g*4 + r;
      ctx[tok*1024 + hoff + c*16 + l16] = f2bf(o);
    }
  }
}

// =============================================================================
extern "C" void kernel_launch(void* const* d_in, const int* in_sizes, int n_in,
                              void* d_out, int out_size, void* d_ws, size_t ws_size,
                              hipStream_t stream){
  (void)in_sizes; (void)n_in; (void)out_size; (void)ws_size;
  const float* x    = (const float*)d_in[0];
  const float* Wq   = (const float*)d_in[1];
  const float* Wk   = (const float*)d_in[2];
  const float* Wv   = (const float*)d_in[3];
  const float* ln1w = (const float*)d_in[4];
  const float* ln1b = (const float*)d_in[5];
  const float* ln2w = (const float*)d_in[6];
  const float* ln2b = (const float*)d_in[7];
  const float* fw1  = (const float*)d_in[8];
  const float* fb1  = (const float*)d_in[9];
  const float* fw2  = (const float*)d_in[10];
  const float* fb2  = (const float*)d_in[11];
  const float* pw   = (const float*)d_in[12];
  const float* pb   = (const float*)d_in[13];

  // d_out (524 MB) doubles as scratch for everything dead before proj_kernel.
  char* ob = (char*)d_out;
  u16* wqt = (u16*)(ob + 0);          // [1024][1024] bf16  (2 MB)
  u16* wkt = (u16*)(ob + 2097152);
  u16* wvt = (u16*)(ob + 4194304);
  u16* w1t = (u16*)(ob + 6291456);    // [4096][1024]       (8 MB)
  u16* w2t = (u16*)(ob + 14680064);   // [1024][4096]       (8 MB)
  u16* xn  = (u16*)(ob + 23068672);   // LN1(x)             (8 MB)
  u16* qbf = (u16*)(ob + 31457280);
  u16* kbf = (u16*)(ob + 39845888);
  u16* vbf = (u16*)(ob + 48234496);
  u16* ctx = (u16*)(ob + 56623104);
  float* h = (float*)(ob + 65011712); // residual fp32      (16 MB)
  u16* hb  = (u16*)(ob + 81788928);   // LN2(h)             (8 MB)
  u16* gbuf= (u16*)(ob + 90177536);   // gelu(ffn1)         (32 MB)

  // proj inputs must NOT alias d_out: keep in d_ws (needs ~74 MB).
  char* wsb = (char*)d_ws;
  u16* pwt = (u16*)(wsb + 0);         // [32000][1024] bf16 (62.5 MB)
  u16* hfb = (u16*)(wsb + 65536000);  // h_final bf16       (8 MB)

  wconv_kernel<<<dim3(32,32)  ,256,0,stream>>>(Wq , wqt, 1024, 1024);
  wconv_kernel<<<dim3(32,32)  ,256,0,stream>>>(Wk , wkt, 1024, 1024);
  wconv_kernel<<<dim3(32,32)  ,256,0,stream>>>(Wv , wvt, 1024, 1024);
  wconv_kernel<<<dim3(128,32) ,256,0,stream>>>(fw1, w1t, 1024, 4096);
  wconv_kernel<<<dim3(32,128) ,256,0,stream>>>(fw2, w2t, 4096, 1024);
  wconv_kernel<<<dim3(1000,32),256,0,stream>>>(pw , pwt, 1024, 32000);

  ln_kernel   <<<4096,256,0,stream>>>(x, ln1w, ln1b, xn);
  qkv_kernel  <<<dim3(32,24),256,0,stream>>>(xn, wqt, wkt, wvt, qbf, kbf, vbf);
  attn_kernel <<<dim3(32,32),256,0,stream>>>(qbf, kbf, vbf, ctx);
  resln_kernel<<<4096,256,0,stream>>>(x, ctx, ln2w, ln2b, h, hb);
  ffn1_kernel <<<dim3(32,32),256,0,stream>>>(hb, w1t, fb1, gbuf);
  ffn2_kernel <<<dim3(64,8) ,256,0,stream>>>(gbuf, w2t, fb2, h, hfb);
  proj_kernel <<<dim3(32,250),256,0,stream>>>(hfb, pwt, pb, (float*)d_out);
}

// Round 2
// 773.409 us; speedup vs baseline: 1.0905x; 1.0905x over previous
//
#include <hip/hip_runtime.h>

using u16 = unsigned short;
typedef __attribute__((ext_vector_type(8))) short bf16x8;
typedef __attribute__((ext_vector_type(4))) float f32x4;

#define DEVI __device__ __forceinline__

DEVI float bf2f(u16 u){ union{ unsigned v; float f; } x; x.v = ((unsigned)u)<<16; return x.f; }
DEVI u16 f2bf(float f){ union{ float f; unsigned v; } x; x.f = f;
  unsigned r = x.v + 0x7FFFu + ((x.v>>16)&1u); return (u16)(r>>16); }

DEVI float gelu_f(float x){
  float y = 0.7978845608028654f*(x + 0.044715f*x*x*x);
  y = fminf(fmaxf(y, -30.f), 30.f);
  float e = __expf(2.f*y);
  return 0.5f*x*(1.f + (e-1.f)/(e+1.f));
}

DEVI void gload_lds16(const void* g, void* l){
  __builtin_amdgcn_global_load_lds((const __attribute__((address_space(1))) void*)g,
                                   (__attribute__((address_space(3))) void*)l, 16, 0, 0);
}

#define BAR __builtin_amdgcn_s_barrier()
#define VM4 asm volatile("s_waitcnt vmcnt(4)" ::: "memory")
#define VM2 asm volatile("s_waitcnt vmcnt(2)" ::: "memory")
#define VM0 asm volatile("s_waitcnt vmcnt(0)" ::: "memory")

// ---------------- weight convert + transpose: in[R][C] f32 -> out[C][R] bf16 ----
__global__ __launch_bounds__(256) void wconv_kernel(const float* __restrict__ in,
                                                    u16* __restrict__ out, int R, int C){
  __shared__ u16 t[32][33];
  int c0 = blockIdx.x*32, r0 = blockIdx.y*32;
  int tc = threadIdx.x & 31, tr = threadIdx.x >> 5;
  #pragma unroll
  for (int i=0;i<4;i++){
    int r = tr + i*8;
    t[r][tc] = f2bf(in[(size_t)(r0+r)*C + (c0+tc)]);
  }
  __syncthreads();
  #pragma unroll
  for (int i=0;i<4;i++){
    int r = tr + i*8;
    out[(size_t)(c0+r)*R + (r0+tc)] = t[tc][r];
  }
}

// ---------------- block reduction (sum, sumsq) over 256 threads --------------
DEVI void block_reduce2(float& s1, float& s2, int tid){
  #pragma unroll
  for (int off=1; off<64; off<<=1){ s1 += __shfl_xor(s1, off); s2 += __shfl_xor(s2, off); }
  __shared__ float red[8];
  int wid = tid>>6;
  if ((tid&63)==0){ red[wid*2]=s1; red[wid*2+1]=s2; }
  __syncthreads();
  s1 = red[0]+red[2]+red[4]+red[6];
  s2 = red[1]+red[3]+red[5]+red[7];
}

__global__ __launch_bounds__(256) void ln_kernel(const float* __restrict__ x,
    const float* __restrict__ w, const float* __restrict__ b, u16* __restrict__ out){
  int row = blockIdx.x, tid = threadIdx.x;
  float4 v = ((const float4*)(x + (size_t)row*1024))[tid];
  float s1 = v.x+v.y+v.z+v.w;
  float s2 = v.x*v.x+v.y*v.y+v.z*v.z+v.w*v.w;
  block_reduce2(s1,s2,tid);
  float mean = s1*(1.f/1024.f);
  float var  = s2*(1.f/1024.f) - mean*mean;
  float inv  = rsqrtf(var + 1e-5f);
  float4 wv = ((const float4*)w)[tid];
  float4 bv = ((const float4*)b)[tid];
  ushort4 o;
  o.x = f2bf(wv.x*((v.x-mean)*inv)+bv.x);
  o.y = f2bf(wv.y*((v.y-mean)*inv)+bv.y);
  o.z = f2bf(wv.z*((v.z-mean)*inv)+bv.z);
  o.w = f2bf(wv.w*((v.w-mean)*inv)+bv.w);
  ((ushort4*)(out + (size_t)row*1024))[tid] = o;
}

__global__ __launch_bounds__(256) void resln_kernel(const float* __restrict__ x,
    const u16* __restrict__ ctx, const float* __restrict__ w, const float* __restrict__ b,
    float* __restrict__ h, u16* __restrict__ hb){
  int row = blockIdx.x, tid = threadIdx.x;
  float4 xv = ((const float4*)(x + (size_t)row*1024))[tid];
  ushort4 cv = ((const ushort4*)(ctx + (size_t)row*1024))[tid];
  float4 hv;
  hv.x = xv.x + bf2f(cv.x); hv.y = xv.y + bf2f(cv.y);
  hv.z = xv.z + bf2f(cv.z); hv.w = xv.w + bf2f(cv.w);
  ((float4*)(h + (size_t)row*1024))[tid] = hv;
  float s1 = hv.x+hv.y+hv.z+hv.w;
  float s2 = hv.x*hv.x+hv.y*hv.y+hv.z*hv.z+hv.w*hv.w;
  block_reduce2(s1,s2,tid);
  float mean = s1*(1.f/1024.f);
  float var  = s2*(1.f/1024.f) - mean*mean;
  float inv  = rsqrtf(var + 1e-5f);
  float4 wv = ((const float4*)w)[tid];
  float4 bv = ((const float4*)b)[tid];
  ushort4 o;
  o.x = f2bf(wv.x*((hv.x-mean)*inv)+bv.x);
  o.y = f2bf(wv.y*((hv.y-mean)*inv)+bv.y);
  o.z = f2bf(wv.z*((hv.z-mean)*inv)+bv.z);
  o.w = f2bf(wv.w*((hv.w-mean)*inv)+bv.w);
  ((ushort4*)(hb + (size_t)row*1024))[tid] = o;
}

// ======================= 256x256 / BK=64 8-phase GEMM core ====================
// A[M,K] bf16 row-major, Bt[N,K] bf16 row-major. 512 thr = 8 waves (2M x 4N).
// LDS 128 KiB (2 dbuf x (A 256x64 + B 256x64)), XOR (row&7)<<4 swizzle, linear
// gload_lds dest + inverse-swizzled global source. Counted vmcnt(4), never 0.
template<class EpiF>
DEVI void gemm8_core(const u16* __restrict__ A, const u16* __restrict__ Bt,
                     int K, int m0, int n0, EpiF epi){
  __shared__ __align__(16) u16 As[2][16384];
  __shared__ __align__(16) u16 Bs[2][16384];
  const int tid = threadIdx.x;
  const int wid = tid>>6, lane = tid&63;
  const int wr = wid>>2, wc = wid&3;       // wave tile: rows wr*128, cols wc*64
  const int g = lane>>4, l16 = lane&15;
  const int wq = wid&3;                    // stager index within A-group
  const int lr = lane>>3, ls = lane&7;

  f32x4 acc[8][4] = {};

  // staging sources (inverse-swizzled slot) + wave-uniform LDS dests
  const u16* aSrc[2][2]; unsigned aDst[2][2];
  #pragma unroll
  for (int qm=0;qm<2;qm++)
    #pragma unroll
    for (int j=0;j<2;j++){
      int r = wr*128 + qm*64 + wq*16 + j*8 + lr;
      aSrc[qm][j] = A + (size_t)(m0 + r)*K + ((ls ^ (r&7))*8);
      aDst[qm][j] = (unsigned)(((wr*128 + qm*64)*8 + (wq*2+j)*64)*16);
    }
  const u16* bSrc[2][2]; unsigned bDst[2][2];
  #pragma unroll
  for (int qn=0;qn<2;qn++)
    #pragma unroll
    for (int j=0;j<2;j++){
      int r = wc*64 + qn*32 + wr*16 + j*8 + lr;
      bSrc[qn][j] = Bt + (size_t)(n0 + r)*K + ((ls ^ (r&7))*8);
      bDst[qn][j] = (unsigned)(((wc*64 + qn*32)*8 + (wr*2+j)*64)*16);
    }

  auto stA = [&](int buf, int qm, int kc){
    char* base = (char*)&As[buf][0];
    #pragma unroll
    for (int j=0;j<2;j++) gload_lds16(aSrc[qm][j] + kc, base + aDst[qm][j]);
  };
  auto stB = [&](int buf, int qn, int kc){
    char* base = (char*)&Bs[buf][0];
    #pragma unroll
    for (int j=0;j<2;j++) gload_lds16(bSrc[qn][j] + kc, base + bDst[qn][j]);
  };
  auto ldA = [&](int buf, int qm, bf16x8 (&a)[4][2]){
    const char* base = (const char*)&As[buf][0];
    #pragma unroll
    for (int i=0;i<4;i++){
      int r = wr*128 + qm*64 + i*16 + l16;
      #pragma unroll
      for (int kk=0;kk<2;kk++)
        a[i][kk] = *(const bf16x8*)(base + r*128 + ((kk*64 + g*16) ^ ((l16&7)<<4)));
    }
  };
  auto ldB = [&](int buf, int qn, bf16x8 (&b)[2][2]){
    const char* base = (const char*)&Bs[buf][0];
    #pragma unroll
    for (int i=0;i<2;i++){
      int r = wc*64 + qn*32 + i*16 + l16;
      #pragma unroll
      for (int kk=0;kk<2;kk++)
        b[i][kk] = *(const bf16x8*)(base + r*128 + ((kk*64 + g*16) ^ ((l16&7)<<4)));
    }
  };
  auto mm = [&](int qm, int qn, bf16x8 (&a)[4][2], bf16x8 (&b)[2][2]){
    __builtin_amdgcn_s_setprio(1);
    #pragma unroll
    for (int i=0;i<4;i++)
      #pragma unroll
      for (int n=0;n<2;n++)
        #pragma unroll
        for (int kk=0;kk<2;kk++)
          acc[qm*4+i][qn*2+n] =
            __builtin_amdgcn_mfma_f32_16x16x32_bf16(a[i][kk], b[n][kk], acc[qm*4+i][qn*2+n], 0,0,0);
    __builtin_amdgcn_s_setprio(0);
  };

  // prologue: tile 0 quarters in consumption-wait order
  stA(0,0,0); stB(0,0,0); stB(0,1,0); stA(0,1,0);
  VM4; BAR;                                   // Aq0,Bq0 of tile 0 landed

  bf16x8 a[4][2], b0[2][2], b1[2][2];
  const int NTile = K>>6;
  for (int t=0; t<NTile-1; ++t){
    const int cur = t&1, nxt = cur^1;
    const int kn = (t+1)<<6;
    // phase 0: quadrant (0,0)
    ldA(cur,0,a); ldB(cur,0,b0);
    stA(nxt,0,kn);
    BAR;
    mm(0,0,a,b0);
    VM4; BAR;                                 // certifies Bq1(t)
    // phase 1: quadrant (0,1)
    ldB(cur,1,b1);
    stB(nxt,0,kn);
    BAR;
    mm(0,1,a,b1);
    VM4; BAR;                                 // certifies Aq1(t)
    // phase 2: quadrant (1,0)
    ldA(cur,1,a);
    stB(nxt,1,kn);
    BAR;
    mm(1,0,a,b0);
    BAR;
    // phase 3: quadrant (1,1)
    stA(nxt,1,kn);
    BAR;
    mm(1,1,a,b1);
    VM4; BAR;                                 // certifies Aq0(t+1),Bq0(t+1)
  }
  { // last tile: no staging; drain waits
    const int cur = (NTile-1)&1;
    ldA(cur,0,a); ldB(cur,0,b0);
    BAR; mm(0,0,a,b0); VM2; BAR;
    ldB(cur,1,b1);
    BAR; mm(0,1,a,b1); VM0; BAR;
    ldA(cur,1,a);
    BAR; mm(1,0,a,b0); BAR;
    mm(1,1,a,b1);
  }
  #pragma unroll
  for (int mf=0;mf<8;mf++)
    #pragma unroll
    for (int nf=0;nf<4;nf++){
      int row = m0 + wr*128 + mf*16 + g*4;
      int col = n0 + wc*64 + nf*16 + l16;
      epi(row, col, acc[mf][nf]);
    }
}

DEVI int xcd_swz(int id, int nwg){ return (id&7)*(nwg>>3) + (id>>3); }  // nwg%8==0

__global__ __launch_bounds__(512,2) void proj8_kernel(const u16* __restrict__ hfb,
    const u16* __restrict__ pwt, const float* __restrict__ pb, float* __restrict__ out){
  int swz = xcd_swz(blockIdx.x, gridDim.x);
  int mt = swz & 15, nt = swz >> 4;          // m-fastest: XCD owns contiguous n-range
  gemm8_core(hfb, pwt, 1024, mt*256, nt*256, [&](int row,int col,f32x4 v){
    float bb = pb[col];
    #pragma unroll
    for (int r=0;r<4;r++) out[(size_t)(row+r)*32000 + col] = v[r] + bb;
  });
}

__global__ __launch_bounds__(512,2) void ffn1_8_kernel(const u16* __restrict__ hb,
    const u16* __restrict__ w1t, const float* __restrict__ b1, u16* __restrict__ gout){
  int swz = xcd_swz(blockIdx.x, gridDim.x);
  int mt = swz & 15, nt = swz >> 4;
  gemm8_core(hb, w1t, 1024, mt*256, nt*256, [&](int row,int col,f32x4 v){
    float bb = b1[col];
    #pragma unroll
    for (int r=0;r<4;r++)
      gout[(size_t)(row+r)*4096 + col] = f2bf(gelu_f(v[r] + bb));
  });
}

__global__ __launch_bounds__(512,2) void qkv8_kernel(const u16* __restrict__ xn,
    const u16* __restrict__ wqt, const u16* __restrict__ wkt, const u16* __restrict__ wvt,
    u16* __restrict__ qo, u16* __restrict__ ko, u16* __restrict__ vo){
  int swz = xcd_swz(blockIdx.x, gridDim.x);
  int mt = swz & 15, ntt = swz >> 4;         // 0..11
  int sel = ntt >> 2;
  const u16* Bt = (sel==0)?wqt:((sel==1)?wkt:wvt);
  u16* out = (sel==0)?qo:((sel==1)?ko:vo);
  gemm8_core(xn, Bt, 1024, mt*256, (ntt&3)*256, [&](int row,int col,f32x4 v){
    #pragma unroll
    for (int r=0;r<4;r++) out[(size_t)(row+r)*1024 + col] = f2bf(v[r]);
  });
}

// ---------------- old m97-style core (kept for ffn2: N=1024, K=4096) ----------
template<int BM,int BN,int WM,int WN, class EpiF>
DEVI void gemm_core(const u16* __restrict__ A, const u16* __restrict__ Bt,
                    int K, int m0, int n0, EpiF epi){
  constexpr int WAVES_N = BN/WN;
  static_assert((BM/WM)*(BN/WN) == 4, "4 waves");
  constexpr int FM = WM/16, FN = WN/16;
  __shared__ u16 As[2][BM*32];
  __shared__ u16 Bs[2][BN*32];
  const int tid = threadIdx.x;
  const int wid = tid>>6, lane = tid&63;
  const int wr = wid / WAVES_N, wc = wid % WAVES_N;
  const int g = lane>>4, l16 = lane&15;
  f32x4 acc[FM][FN] = {};

  auto stage = [&](int buf, int t){
    #pragma unroll
    for (int j=0;j<BM/64;j++){
      int cbase = wid*BM + j*64;
      int c = cbase + lane;
      int r = c>>2, c4 = c&3;
      gload_lds16(A + (size_t)(m0+r)*K + t*32 + c4*8, &As[buf][cbase*8]);
    }
    #pragma unroll
    for (int j=0;j<BN/64;j++){
      int cbase = wid*BN + j*64;
      int c = cbase + lane;
      int r = c>>2, c4 = c&3;
      gload_lds16(Bt + (size_t)(n0+r)*K + t*32 + c4*8, &Bs[buf][cbase*8]);
    }
  };

  const int NT = K/32;
  stage(0,0);
  __syncthreads();
  for (int t=0;t<NT;t++){
    int cur = t&1;
    if (t+1 < NT) stage(cur^1, t+1);
    bf16x8 a[FM], b[FN];
    #pragma unroll
    for (int m=0;m<FM;m++) a[m] = *(const bf16x8*)&As[cur][(wr*WM + m*16 + l16)*32 + g*8];
    #pragma unroll
    for (int n=0;n<FN;n++) b[n] = *(const bf16x8*)&Bs[cur][(wc*WN + n*16 + l16)*32 + g*8];
    #pragma unroll
    for (int m=0;m<FM;m++)
      #pragma unroll
      for (int n=0;n<FN;n++)
        acc[m][n] = __builtin_amdgcn_mfma_f32_16x16x32_bf16(a[m], b[n], acc[m][n], 0,0,0);
    __syncthreads();
  }
  #pragma unroll
  for (int m=0;m<FM;m++)
    #pragma unroll
    for (int n=0;n<FN;n++){
      int row = m0 + wr*WM + m*16 + g*4;
      int col = n0 + wc*WN + n*16 + l16;
      epi(row, col, acc[m][n]);
    }
}

__global__ __launch_bounds__(256) void ffn2_kernel(const u16* __restrict__ gin,
    const u16* __restrict__ w2t, const float* __restrict__ b2,
    const float* __restrict__ h, u16* __restrict__ hfb){
  gemm_core<64,128,32,64>(gin, w2t, 4096, blockIdx.x*64, blockIdx.y*128,
    [&](int row,int col,f32x4 v){
      #pragma unroll
      for (int r=0;r<4;r++){
        float t = h[(size_t)(row+r)*1024 + col] + v[r] + b2[col];
        hfb[(size_t)(row+r)*1024 + col] = f2bf(t);
      }
    });
}

// ---------------- flash attention: B=2,H=16,S=2048,D=64, causal ---------------
__global__ __launch_bounds__(256) void attn_kernel(const u16* __restrict__ q,
    const u16* __restrict__ k, const u16* __restrict__ v, u16* __restrict__ ctx){
  __shared__ u16 Qs[64*64], Ks[64*64], Vt[64*64];
  __shared__ u16 Ps[4][16*64];
  const int tid = threadIdx.x, lane = tid&63, wid = tid>>6;
  const int g = lane>>4, l16 = lane&15;
  const int b = blockIdx.x>>4, hh = blockIdx.x&15;
  const int qb = blockIdx.y;
  const size_t tokbase = (size_t)b*2048;
  const int hoff = hh*64;

  #pragma unroll
  for (int j=0;j<2;j++){
    int c = j*256 + tid;
    int r = c>>3, c8 = c&7;
    uint4 val = *(const uint4*)(q + (tokbase + qb*64 + r)*1024 + hoff + c8*8);
    *(uint4*)((char*)Qs + r*128 + ((c8*16) ^ ((r&7)<<4))) = val;
  }
  __syncthreads();
  bf16x8 qa[2];
  const int qrow_l = wid*16 + l16;
  #pragma unroll
  for (int kk=0;kk<2;kk++)
    qa[kk] = *(const bf16x8*)((const char*)Qs + qrow_l*128 + ((kk*64 + g*16) ^ ((qrow_l&7)<<4)));

  float m_r[4], l_r[4];
  f32x4 o_acc[4] = {};
  #pragma unroll
  for (int r=0;r<4;r++){ m_r[r] = -1e30f; l_r[r] = 0.f; }

  for (int kt=0; kt<=qb; kt++){
    __syncthreads();
    const int kv0 = kt*64;
    #pragma unroll
    for (int j=0;j<2;j++){
      int c = j*256 + tid;
      int r = c>>3, c8 = c&7;
      uint4 val = *(const uint4*)(k + (tokbase + kv0 + r)*1024 + hoff + c8*8);
      *(uint4*)((char*)Ks + r*128 + ((c8*16) ^ ((r&7)<<4))) = val;
    }
    #pragma unroll
    for (int j=0;j<2;j++){
      int c = j*256 + tid;
      int kv = c>>3, d8 = c&7;
      union{ uint4 u; u16 s[8]; } uu;
      uu.u = *(const uint4*)(v + (tokbase + kv0 + kv)*1024 + hoff + d8*8);
      #pragma unroll
      for (int e=0;e<8;e++){
        int d = d8*8+e;
        *(u16*)((char*)Vt + d*128 + ((kv*2) ^ ((d&7)<<4))) = uu.s[e];
      }
    }
    __syncthreads();

    f32x4 s[4] = {};
    #pragma unroll
    for (int c=0;c<4;c++){
      #pragma unroll
      for (int kk=0;kk<2;kk++){
        int krow = c*16 + l16;
        bf16x8 kb = *(const bf16x8*)((const char*)Ks + krow*128 + ((kk*64 + g*16) ^ ((krow&7)<<4)));
        s[c] = __builtin_amdgcn_mfma_f32_16x16x32_bf16(qa[kk], kb, s[c], 0,0,0);
      }
    }
    const int qrow0 = qb*64 + wid*16 + g*4;
    float sv[4][4];
    #pragma unroll
    for (int c=0;c<4;c++){
      #pragma unroll
      for (int r=0;r<4;r++){
        float xx = s[c][r] * 0.125f;
        if (kt==qb){
          int kvabs = kv0 + c*16 + l16;
          if (kvabs > qrow0 + r) xx = -1e30f;
        }
        sv[c][r] = xx;
      }
    }
    #pragma unroll
    for (int r=0;r<4;r++){
      float rm = fmaxf(fmaxf(sv[0][r],sv[1][r]),fmaxf(sv[2][r],sv[3][r]));
      #pragma unroll
      for (int off=1; off<16; off<<=1) rm = fmaxf(rm, __shfl_xor(rm, off));
      float mn  = fmaxf(m_r[r], rm);
      float fac = __expf(m_r[r] - mn);
      float rs = 0.f;
      const int prow = g*4 + r;
      #pragma unroll
      for (int c=0;c<4;c++){
        float p = __expf(sv[c][r] - mn);
        rs += p;
        *(u16*)((char*)&Ps[wid][0] + prow*128 + (((c*16+l16)*2) ^ ((prow&7)<<4))) = f2bf(p);
      }
      #pragma unroll
      for (int off=1; off<16; off<<=1) rs += __shfl_xor(rs, off);
      m_r[r] = mn;
      l_r[r] = l_r[r]*fac + rs;
      #pragma unroll
      for (int c=0;c<4;c++) o_acc[c][r] *= fac;
    }
    bf16x8 pa[2];
    #pragma unroll
    for (int kk=0;kk<2;kk++)
      pa[kk] = *(const bf16x8*)((const char*)&Ps[wid][0] + l16*128 + ((kk*64 + g*16) ^ ((l16&7)<<4)));
    #pragma unroll
    for (int c=0;c<4;c++){
      #pragma unroll
      for (int kk=0;kk<2;kk++){
        int vrow = c*16 + l16;
        bf16x8 vb = *(const bf16x8*)((const char*)Vt + vrow*128 + ((kk*64 + g*16) ^ ((vrow&7)<<4)));
        o_acc[c] = __builtin_amdgcn_mfma_f32_16x16x32_bf16(pa[kk], vb, o_acc[c], 0,0,0);
      }
    }
  }
  #pragma unroll
  for (int c=0;c<4;c++){
    #pragma unroll
    for (int r=0;r<4;r++){
      float o = o_acc[c][r] / l_r[r];
      size_t tok = tokbase + qb*64 + wid*16 + g*4 + r;
      ctx[tok*1024 + hoff + c*16 + l16] = f2bf(o);
    }
  }
}

// =============================================================================
extern "C" void kernel_launch(void* const* d_in, const int* in_sizes, int n_in,
                              void* d_out, int out_size, void* d_ws, size_t ws_size,
                              hipStream_t stream){
  (void)in_sizes; (void)n_in; (void)out_size; (void)ws_size;
  const float* x    = (const float*)d_in[0];
  const float* Wq   = (const float*)d_in[1];
  const float* Wk   = (const float*)d_in[2];
  const float* Wv   = (const float*)d_in[3];
  const float* ln1w = (const float*)d_in[4];
  const float* ln1b = (const float*)d_in[5];
  const float* ln2w = (const float*)d_in[6];
  const float* ln2b = (const float*)d_in[7];
  const float* fw1  = (const float*)d_in[8];
  const float* fb1  = (const float*)d_in[9];
  const float* fw2  = (const float*)d_in[10];
  const float* fb2  = (const float*)d_in[11];
  const float* pw   = (const float*)d_in[12];
  const float* pb   = (const float*)d_in[13];

  char* ob = (char*)d_out;
  u16* wqt = (u16*)(ob + 0);
  u16* wkt = (u16*)(ob + 2097152);
  u16* wvt = (u16*)(ob + 4194304);
  u16* w1t = (u16*)(ob + 6291456);
  u16* w2t = (u16*)(ob + 14680064);
  u16* xn  = (u16*)(ob + 23068672);
  u16* qbf = (u16*)(ob + 31457280);
  u16* kbf = (u16*)(ob + 39845888);
  u16* vbf = (u16*)(ob + 48234496);
  u16* ctx = (u16*)(ob + 56623104);
  float* h = (float*)(ob + 65011712);
  u16* hb  = (u16*)(ob + 81788928);
  u16* gbuf= (u16*)(ob + 90177536);

  char* wsb = (char*)d_ws;
  u16* pwt = (u16*)(wsb + 0);
  u16* hfb = (u16*)(wsb + 65536000);

  wconv_kernel<<<dim3(32,32)  ,256,0,stream>>>(Wq , wqt, 1024, 1024);
  wconv_kernel<<<dim3(32,32)  ,256,0,stream>>>(Wk , wkt, 1024, 1024);
  wconv_kernel<<<dim3(32,32)  ,256,0,stream>>>(Wv , wvt, 1024, 1024);
  wconv_kernel<<<dim3(128,32) ,256,0,stream>>>(fw1, w1t, 1024, 4096);
  wconv_kernel<<<dim3(32,128) ,256,0,stream>>>(fw2, w2t, 4096, 1024);
  wconv_kernel<<<dim3(1000,32),256,0,stream>>>(pw , pwt, 1024, 32000);

  ln_kernel    <<<4096,256,0,stream>>>(x, ln1w, ln1b, xn);
  qkv8_kernel  <<<192,512,0,stream>>>(xn, wqt, wkt, wvt, qbf, kbf, vbf);
  attn_kernel  <<<dim3(32,32),256,0,stream>>>(qbf, kbf, vbf, ctx);
  resln_kernel <<<4096,256,0,stream>>>(x, ctx, ln2w, ln2b, h, hb);
  ffn1_8_kernel<<<256,512,0,stream>>>(hb, w1t, fb1, gbuf);
  ffn2_kernel  <<<dim3(64,8) ,256,0,stream>>>(gbuf, w2t, fb2, h, hfb);
  proj8_kernel <<<2000,512,0,stream>>>(hfb, pwt, pb, (float*)d_out);
}